// Round 4
// baseline (193.868 us; speedup 1.0000x reference)
//
#include <hip/hip_runtime.h>
#include <hip/hip_bf16.h>
#include <cstdint>
#include <cstddef>

// Sizes fixed by the reference problem.
#define DMODEL 1024
#define BATCH  4
#define SEQ    4096
#define BSROWS (BATCH*SEQ)     // 16384
#define CHUNK  32
#define NCHUNK (SEQ/CHUNK)     // 128
#define NCH_T  (BATCH*NCHUNK)  // 512 total chunks

typedef __attribute__((ext_vector_type(8))) short bf16x8;
typedef __attribute__((ext_vector_type(4))) float f32x4;

// ---- helpers ---------------------------------------------------------------

__device__ __forceinline__ unsigned short f2bf(float f) {
  union { float f; uint32_t u; } v; v.f = f;
  uint32_t u = v.u;
  u += 0x7FFFu + ((u >> 16) & 1u);   // round-to-nearest-even
  return (unsigned short)(u >> 16);
}

__device__ __forceinline__ float sigmoid_dev(const float* dp) {
  return 1.0f / (1.0f + expf(-dp[0]));
}

typedef __attribute__((address_space(1))) void void_g;
typedef __attribute__((address_space(3))) void void_l;

__device__ __forceinline__ void gl2lds16(const void* g, void* l) {
  __builtin_amdgcn_global_load_lds((void_g*)g, (void_l*)l, 16, 0, 0);
}

// ---- 64x64-tile NT K-loop (BK=64, XOR-8 swizzle) — used by mid2/pout -------
// Ring-3 LDS pipeline, counted vmcnt(4), raw s_barrier, 1 barrier per K-step.
// (Unchanged from the round-3 passing kernel.)
__device__ __forceinline__ void kloop64(
    const unsigned short* __restrict__ A, const unsigned short* __restrict__ B,
    int m0, int n0, f32x4 acc[2][2],
    unsigned short* As, unsigned short* Bs, int tid) {
  int lane = tid & 63, w = tid >> 6, wm = w & 1, wn = w >> 1;
  int quad = lane >> 4, l16 = lane & 15;
  int r = tid >> 3, cch = tid & 7;
  int g = cch ^ (r & 7);

  auto stage = [&](int t, int slot) {
    int k0 = t * 64;
    unsigned short* dA = As + slot * 4096;
    unsigned short* dB = Bs + slot * 4096;
    gl2lds16(A + (size_t)(m0 + r) * DMODEL + k0 + g * 8,      dA + r * 64 + cch * 8);
    gl2lds16(A + (size_t)(m0 + 32 + r) * DMODEL + k0 + g * 8, dA + (32 + r) * 64 + cch * 8);
    gl2lds16(B + (size_t)(n0 + r) * DMODEL + k0 + g * 8,      dB + r * 64 + cch * 8);
    gl2lds16(B + (size_t)(n0 + 32 + r) * DMODEL + k0 + g * 8, dB + (32 + r) * 64 + cch * 8);
  };
  auto compute = [&](int slot) {
    const bf16x8* Av = (const bf16x8*)(As + slot * 4096);
    const bf16x8* Bv = (const bf16x8*)(Bs + slot * 4096);
    #pragma unroll
    for (int kk = 0; kk < 2; ++kk) {
      bf16x8 af[2], bfr[2];
      #pragma unroll
      for (int i = 0; i < 2; ++i) {
        int rowA = wm * 32 + i * 16 + l16;
        af[i]  = Av[rowA * 8 + ((kk * 4 + quad) ^ (l16 & 7))];
        int rowB = wn * 32 + i * 16 + l16;
        bfr[i] = Bv[rowB * 8 + ((kk * 4 + quad) ^ (l16 & 7))];
      }
      __builtin_amdgcn_s_setprio(1);
      #pragma unroll
      for (int i = 0; i < 2; ++i)
        #pragma unroll
        for (int j = 0; j < 2; ++j)
          acc[i][j] = __builtin_amdgcn_mfma_f32_16x16x32_bf16(af[i], bfr[j], acc[i][j], 0, 0, 0);
      __builtin_amdgcn_s_setprio(0);
    }
  };

  stage(0, 0); stage(1, 1);
  asm volatile("s_waitcnt vmcnt(4)" ::: "memory");
  __builtin_amdgcn_s_barrier();
  asm volatile("" ::: "memory");
  int cur = 0;
  for (int t = 0; t < 14; ++t) {
    int ns = cur + 2; if (ns >= 3) ns -= 3;
    stage(t + 2, ns);
    compute(cur);
    asm volatile("s_waitcnt vmcnt(4)" ::: "memory");
    __builtin_amdgcn_s_barrier();
    asm volatile("" ::: "memory");
    cur = (cur == 2) ? 0 : cur + 1;
  }
  compute(cur);                                        // tile 14
  asm volatile("s_waitcnt vmcnt(0)" ::: "memory");
  __builtin_amdgcn_s_barrier();
  asm volatile("" ::: "memory");
  cur = (cur == 2) ? 0 : cur + 1;
  compute(cur);                                        // tile 15
}

// ---- fused prep ------------------------------------------------------------
// blocks [0,512)    : single-pass local scan: hv = local scan (bf16) + carry
// blocks [512,1536) : W_f row e = blk-512 -> bf16, fused bb[e]=dot(W_f[e],b_up)
// blocks [1536,2560): W_up f32 [c][d] -> bf16 transposed [d][c] (ushort4 store)
// blocks [2560,2624): lbeta/cbeta via 5-step Kogge-Stone shuffle scan
__global__ __launch_bounds__(256) void prep_kernel(
    const float* __restrict__ x, const float* __restrict__ mask,
    const float* __restrict__ W_up, const float* __restrict__ b_up,
    const float* __restrict__ W_f, const float* __restrict__ dp,
    unsigned short* __restrict__ Wf_bf, unsigned short* __restrict__ WupT,
    float* __restrict__ bb, unsigned short* __restrict__ hv,
    float* __restrict__ carry, float* __restrict__ lbeta,
    float* __restrict__ cbeta) {
  __shared__ float tile[32][33];
  int blk = blockIdx.x;
  int tid = threadIdx.x;

  if (blk < 512) {
    float decay = sigmoid_dev(dp);
    int b = blk / NCHUNK, c = blk % NCHUNK;
    int base = b * SEQ + c * CHUNK;
    const float4* xp = (const float4*)(x + (size_t)base * DMODEL);
    const float4* mp4 = (const float4*)(mask + base);
    float mreg[32];
    #pragma unroll
    for (int q = 0; q < 8; ++q) {
      float4 t = mp4[q];
      mreg[q * 4 + 0] = t.x; mreg[q * 4 + 1] = t.y;
      mreg[q * 4 + 2] = t.z; mreg[q * 4 + 3] = t.w;
    }
    float4 h = make_float4(0.f, 0.f, 0.f, 0.f);
    #pragma unroll
    for (int s = 0; s < CHUNK; ++s) {
      float m = mreg[s];
      float4 xv = xp[(size_t)s * (DMODEL / 4) + tid];
      h.x = decay * h.x + m * xv.x;
      h.y = decay * h.y + m * xv.y;
      h.z = decay * h.z + m * xv.z;
      h.w = decay * h.w + m * xv.w;
      ushort4 o;
      o.x = f2bf(h.x); o.y = f2bf(h.y); o.z = f2bf(h.z); o.w = f2bf(h.w);
      ((ushort4*)hv)[(size_t)(base + s) * (DMODEL / 4) + tid] = o;
    }
    ((float4*)carry)[(size_t)blk * (DMODEL / 4) + tid] = h;
  } else if (blk < 1536) {
    int e = blk - 512;
    int lane = tid & 63, w = tid >> 6;
    float4 v = ((const float4*)(W_f + (size_t)e * DMODEL))[tid];
    float4 bu = ((const float4*)b_up)[tid];
    ushort4 o;
    o.x = f2bf(v.x); o.y = f2bf(v.y); o.z = f2bf(v.z); o.w = f2bf(v.w);
    ((ushort4*)(Wf_bf + (size_t)e * DMODEL))[tid] = o;
    float s = v.x * bu.x + v.y * bu.y + v.z * bu.z + v.w * bu.w;
    #pragma unroll
    for (int off = 32; off; off >>= 1) s += __shfl_down(s, off);
    if (lane == 0) ((float*)tile)[w] = s;
    __syncthreads();
    if (tid == 0)
      bb[e] = ((float*)tile)[0] + ((float*)tile)[1] +
              ((float*)tile)[2] + ((float*)tile)[3];
  } else if (blk < 2560) {
    // transpose 32x32 tile; vectorized ushort4 store (was scalar 2 B stores)
    int id = blk - 1536;
    int bx = id & 31, by = id >> 5;
    int tx = tid & 31, ty = tid >> 5;   // 32 x 8
    int xx = bx * 32 + tx;
    int y0 = by * 32;
    for (int j = ty; j < 32; j += 8)
      tile[j][tx] = W_up[(size_t)(y0 + j) * DMODEL + xx];
    __syncthreads();
    // WupT[d][c] = W_up[c][d]; d = bx*32+dd, c = y0+c4..c4+3
    int dd = tid >> 3;            // 0..31
    int c4 = (tid & 7) * 4;       // 0,4,...,28
    ushort4 o;
    o.x = f2bf(tile[c4 + 0][dd]);
    o.y = f2bf(tile[c4 + 1][dd]);
    o.z = f2bf(tile[c4 + 2][dd]);
    o.w = f2bf(tile[c4 + 3][dd]);
    *(ushort4*)(WupT + (size_t)(bx * 32 + dd) * DMODEL + y0 + c4) = o;
  } else {
    // beta local scans: h_s = sum_{i<=s} decay^(s-i) * m_i over 32-row chunks.
    // Kogge-Stone with constant coefficient: 5 shuffle steps instead of a
    // 32-iteration serial loop. Segments (32) are wave-aligned (256 % 32 == 0).
    float decay = sigmoid_dev(dp);
    int t = (blk - 2560) * 256 + tid;     // 0..16383 global row
    int s = t & 31;
    float h = mask[t];                    // coalesced
    float wgt = decay;                    // decay^off, off = 1,2,4,8,16
    #pragma unroll
    for (int off = 1; off < 32; off <<= 1) {
      float up = __shfl_up(h, off);
      if (s >= off) h += wgt * up;
      wgt = wgt * wgt;
    }
    lbeta[t] = h;
    if (s == 31) cbeta[t >> 5] = h;
  }
}

// ---- mid2: gemm_wc (256 blocks, 64x64) + chunk-level scan (16 blocks) ------
__global__ __launch_bounds__(256) void mid2_kernel(
    const unsigned short* __restrict__ Wf_bf,
    const unsigned short* __restrict__ WupT,
    unsigned short* __restrict__ Wc,
    const float* __restrict__ carry, const float* __restrict__ cbeta,
    const float* __restrict__ dp,
    unsigned short* __restrict__ Pbf, float* __restrict__ pbeta) {
  __shared__ unsigned short As[3 * 64 * 64];   // 24 KB (ring-3)
  __shared__ unsigned short Bs[3 * 64 * 64];   // 24 KB
  int tid = threadIdx.x;
  if (blockIdx.x < 256) {
    int mt = blockIdx.x >> 4, nt = blockIdx.x & 15;
    f32x4 acc[2][2] = {};
    kloop64(Wf_bf, WupT, mt * 64, nt * 64, acc, As, Bs, tid);
    int lane = tid & 63, w = tid >> 6, wm = w & 1, wn = w >> 1;
    int quad = lane >> 4, l16 = lane & 15;
    #pragma unroll
    for (int j = 0; j < 2; ++j) {
      int col = nt * 64 + wn * 32 + j * 16 + l16;
      #pragma unroll
      for (int i = 0; i < 2; ++i) {
        int rowb = mt * 64 + wm * 32 + i * 16 + quad * 4;
        #pragma unroll
        for (int rr = 0; rr < 4; ++rr)
          Wc[(size_t)(rowb + rr) * DMODEL + col] = f2bf(acc[i][j][rr]);
      }
    }
  } else {
    float decay = sigmoid_dev(dp);
    float dL = powf(decay, (float)CHUNK);
    int gid = (blockIdx.x - 256) * 256 + tid;   // 0 .. 4095
    int b = gid >> 10, dd = gid & 1023;
    float P = 0.f;
    for (int c0 = 0; c0 < NCHUNK; c0 += 8) {
      float v[8];
      #pragma unroll
      for (int j = 0; j < 8; ++j)
        v[j] = carry[(size_t)(b * NCHUNK + c0 + j) * DMODEL + dd];
      #pragma unroll
      for (int j = 0; j < 8; ++j) {
        Pbf[(size_t)(b * NCHUNK + c0 + j) * DMODEL + dd] = f2bf(P);
        P = dL * P + v[j];
      }
    }
    if (dd == 0) {
      float Pb = 0.f;
      for (int c0 = 0; c0 < NCHUNK; c0 += 16) {
        float v[16];
        #pragma unroll
        for (int j = 0; j < 16; ++j) v[j] = cbeta[b * NCHUNK + c0 + j];
        #pragma unroll
        for (int j = 0; j < 16; ++j) {
          pbeta[b * NCHUNK + c0 + j] = Pb;
          Pb = dL * Pb + v[j];
        }
      }
    }
  }
}

// ---- pout: Pout[c][e] = sum_d Pbf[c][d]*Wc[e][d] + pbeta[c]*bb[e] ----------
__global__ __launch_bounds__(256) void pout_kernel(
    const unsigned short* __restrict__ Pbf,
    const unsigned short* __restrict__ Wc,
    const float* __restrict__ pbeta, const float* __restrict__ bb,
    float* __restrict__ Pout) {
  __shared__ unsigned short As[3 * 64 * 64];   // 24 KB (ring-3)
  __shared__ unsigned short Bs[3 * 64 * 64];   // 24 KB
  int tid = threadIdx.x;
  int mt = blockIdx.x >> 4, nt = blockIdx.x & 15;  // 8 x 16
  f32x4 acc[2][2] = {};
  kloop64(Pbf, Wc, mt * 64, nt * 64, acc, As, Bs, tid);
  int lane = tid & 63, w = tid >> 6, wm = w & 1, wn = w >> 1;
  int quad = lane >> 4, l16 = lane & 15;
  #pragma unroll
  for (int j = 0; j < 2; ++j) {
    int col = nt * 64 + wn * 32 + j * 16 + l16;
    float bbv = bb[col];
    #pragma unroll
    for (int i = 0; i < 2; ++i) {
      int rowb = mt * 64 + wm * 32 + i * 16 + quad * 4;
      #pragma unroll
      for (int rr = 0; rr < 4; ++rr) {
        int row = rowb + rr;
        Pout[(size_t)row * DMODEL + col] = acc[i][j][rr] + pbeta[row] * bbv;
      }
    }
  }
}

// ---- main GEMM: out = hv@Wc^T + decay^(s+1)*Pout[chunk] + lbeta*bb + b_f ---
// 256x256 tile, 512 threads (8 waves, 2M x 4N), BK=32, ring-4 LDS (128 KB,
// 1 block/CU, grid = 256 = 1/CU exactly). NEW (r4): m201-style dual-barrier
// fine phases. Each K-step = 2 phases; each phase:
//   {ds_read subtile || stage quarter-tile} -> s_barrier -> lgkmcnt(0)
//   -> setprio(1) 16xMFMA setprio(0) -> s_barrier
// vmcnt(8) once per K-step (ring-4 ledger: tile t+1 forced landed, t+2/t+3
// stay in flight — never drained to 0 in the loop). Round-3 coarse 2-phase
// kept waves in lockstep (25% MfmaUtil, ~3000cy/K-step vs ~1000cy pipe work);
// the per-phase barrier pair creates the wave role-split (T3 gates T5).
__global__ __launch_bounds__(512) void gemm_main(
    const unsigned short* __restrict__ A,    // hv (local scans) bf16 [16384][1024]
    const unsigned short* __restrict__ Bm,   // Wc bf16 [1024][1024] rows=e
    const float* __restrict__ Pout,          // [512][1024]
    const float* __restrict__ lbeta,
    const float* __restrict__ bb,
    const float* __restrict__ bias_f,
    const float* __restrict__ dp,
    float* __restrict__ out) {
  __shared__ unsigned short As[4 * 256 * 32];   // 64 KB (ring-4)
  __shared__ unsigned short Bs[4 * 256 * 32];   // 64 KB
  __shared__ float dpow[CHUNK];
  const int SLOT = 256 * 32;
  int tid = threadIdx.x;
  if (tid < CHUNK) {
    float decay = sigmoid_dev(dp);
    dpow[tid] = powf(decay, (float)(tid + 1));
  }
  __syncthreads();   // full drain once; dpow visible for epilogue

  int lane = tid & 63, wid = tid >> 6;
  int wm = wid >> 2, wn = wid & 3;            // 2M x 4N waves
  int quad = lane >> 4, l16 = lane & 15;
  int phi = (l16 >> 1) & 3;                   // reader-side swizzle
  int r = tid >> 2, c4 = tid & 3;             // staging: 128 rows x 4 chunks
  int g = c4 ^ ((r >> 1) & 3);                // pre-swizzled global chunk

  // XCD-aware mapping: each XCD owns 8 contiguous m-tiles x all 4 n-tiles.
  int bid = blockIdx.x;
  int xcd = bid & 7, jb = bid >> 3;
  int m0 = (xcd * 8 + (jb >> 2)) * 256;       // 64 m-tiles
  int n0 = (jb & 3) * 256;                    // 4 n-tiles

  f32x4 acc[8][4] = {};
  bf16x8 bfr[4];

  auto stageA = [&](int t, int slot) {
    int k0 = t * 32;
    unsigned short* dA = As + slot * SLOT;
    gl2lds16(A + (size_t)(m0 + r) * DMODEL + k0 + g * 8,        dA + r * 32 + c4 * 8);
    gl2lds16(A + (size_t)(m0 + 128 + r) * DMODEL + k0 + g * 8,  dA + (128 + r) * 32 + c4 * 8);
  };
  auto stageB = [&](int t, int slot) {
    int k0 = t * 32;
    unsigned short* dB = Bs + slot * SLOT;
    gl2lds16(Bm + (size_t)(n0 + r) * DMODEL + k0 + g * 8,       dB + r * 32 + c4 * 8);
    gl2lds16(Bm + (size_t)(n0 + 128 + r) * DMODEL + k0 + g * 8, dB + (128 + r) * 32 + c4 * 8);
  };
  auto readA = [&](const bf16x8* Av, int mh, bf16x8 af[4]) {
    #pragma unroll
    for (int i = 0; i < 4; ++i) {
      int rowA = wm * 128 + mh * 64 + i * 16 + l16;
      af[i] = Av[rowA * 4 + (quad ^ phi)];
    }
  };
  auto readB = [&](const bf16x8* Bv) {
    #pragma unroll
    for (int j = 0; j < 4; ++j) {
      int rowB = wn * 64 + j * 16 + l16;
      bfr[j] = Bv[rowB * 4 + (quad ^ phi)];
    }
  };
  auto mfma16 = [&](int mh, const bf16x8 af[4]) {
    __builtin_amdgcn_s_setprio(1);
    #pragma unroll
    for (int i = 0; i < 4; ++i)
      #pragma unroll
      for (int j = 0; j < 4; ++j)
        acc[mh * 4 + i][j] =
            __builtin_amdgcn_mfma_f32_16x16x32_bf16(af[i], bfr[j], acc[mh * 4 + i][j], 0, 0, 0);
    __builtin_amdgcn_s_setprio(0);
  };

  // Prologue: tiles 0,1,2 staged (12 loads); vmcnt(8) -> tile 0 landed.
  stageA(0, 0); stageB(0, 0);
  stageA(1, 1); stageB(1, 1);
  stageA(2, 2); stageB(2, 2);
  asm volatile("s_waitcnt vmcnt(8)" ::: "memory");
  __builtin_amdgcn_s_barrier();
  asm volatile("" ::: "memory");

  // Main loop: t = 0..28 stages t+3 into slot (t+3)&3 == (t-1)&3 (consumed &
  // lgkm-drained by all waves before the end-of-(t-1) barrier). vmcnt(8) at
  // the phase-2 pre-MFMA boundary: newest 8 outstanding = {A,B}(t+2),{A,B}(t+3)
  // -> tile t+1 landed for this wave; following barrier collectivizes.
  for (int t = 0; t < 29; ++t) {
    int cs = t & 3, ss = (t + 3) & 3;
    const bf16x8* Av = (const bf16x8*)(As + cs * SLOT);
    const bf16x8* Bv = (const bf16x8*)(Bs + cs * SLOT);
    // ---- phase 1: reads A-half0 + B, stage A(t+3), MFMA half0 ----
    bf16x8 af[4];
    readA(Av, 0, af);
    readB(Bv);
    stageA(t + 3, ss);
    __builtin_amdgcn_s_barrier();
    asm volatile("s_waitcnt lgkmcnt(0)" ::: "memory");
    __builtin_amdgcn_sched_barrier(0);
    mfma16(0, af);
    __builtin_amdgcn_s_barrier();
    // ---- phase 2: reads A-half1, stage B(t+3), vmcnt(8), MFMA half1 ----
    bf16x8 af2[4];
    readA(Av, 1, af2);
    stageB(t + 3, ss);
    asm volatile("s_waitcnt vmcnt(8)" ::: "memory");
    __builtin_amdgcn_s_barrier();
    asm volatile("s_waitcnt lgkmcnt(0)" ::: "memory");
    __builtin_amdgcn_sched_barrier(0);
    mfma16(1, af2);
    __builtin_amdgcn_s_barrier();
    asm volatile("" ::: "memory");
  }
  // Tail: tiles 29,30,31 (slots 1,2,3) — no staging; drain 8 -> 4 -> 0.
  auto tailfull = [&](int slot) {
    const bf16x8* Av = (const bf16x8*)(As + slot * SLOT);
    const bf16x8* Bv = (const bf16x8*)(Bs + slot * SLOT);
    bf16x8 af[4];
    readA(Av, 0, af);
    readB(Bv);
    mfma16(0, af);
    readA(Av, 1, af);
    mfma16(1, af);
  };
  tailfull(1);
  asm volatile("s_waitcnt vmcnt(4)" ::: "memory");
  __builtin_amdgcn_s_barrier();
  asm volatile("" ::: "memory");
  tailfull(2);
  asm volatile("s_waitcnt vmcnt(0)" ::: "memory");
  __builtin_amdgcn_s_barrier();
  asm volatile("" ::: "memory");
  tailfull(3);

  // Epilogue — j innermost: 16-lane groups write 4 consecutive 64 B segments
  // per row; lbeta/dpow hoisted per row.
  float bbv[4], bfv[4];
  #pragma unroll
  for (int j = 0; j < 4; ++j) {
    int col = n0 + wn * 64 + j * 16 + l16;
    bbv[j] = bb[col];
    bfv[j] = bias_f[col];
  }
  #pragma unroll
  for (int i = 0; i < 8; ++i) {
    #pragma unroll
    for (int rr = 0; rr < 4; ++rr) {
      int row = m0 + wm * 128 + i * 16 + quad * 4 + rr;
      float lb  = lbeta[row];
      float dpw = dpow[row & 31];
      const float* poRow = Pout + (size_t)(row >> 5) * DMODEL;
      float* outRow = out + (size_t)row * DMODEL;
      #pragma unroll
      for (int j = 0; j < 4; ++j) {
        int col = n0 + wn * 64 + j * 16 + l16;
        outRow[col] = acc[i][j][rr] + dpw * poRow[col] + lb * bbv[j] + bfv[j];
      }
    }
  }
}

// ---- launch ----------------------------------------------------------------

extern "C" void kernel_launch(void* const* d_in, const int* in_sizes, int n_in,
                              void* d_out, int out_size, void* d_ws, size_t ws_size,
                              hipStream_t stream) {
  const float* x    = (const float*)d_in[0];
  const float* mask = (const float*)d_in[1];
  const float* W_up = (const float*)d_in[2];
  const float* b_up = (const float*)d_in[3];
  const float* W_f  = (const float*)d_in[4];
  const float* b_f  = (const float*)d_in[5];
  const float* dp   = (const float*)d_in[6];
  float* out = (float*)d_out;

  char* ws = (char*)d_ws;
  unsigned short* hv    = (unsigned short*)(ws);                 // 32 MB
  unsigned short* Wc    = (unsigned short*)(ws + 33554432);      // 2 MB
  unsigned short* Wf_bf = (unsigned short*)(ws + 35651584);      // 2 MB
  unsigned short* WupT  = (unsigned short*)(ws + 37748736);      // 2 MB
  float* carry  = (float*)(ws + 39845888);                       // 2 MB
  unsigned short* Pbf = (unsigned short*)(ws + 41943040);        // 1 MB
  float* Pout   = (float*)(ws + 42991616);                       // 2 MB
  float* lbeta  = (float*)(ws + 45088768);                       // 64 KB
  float* cbeta  = (float*)(ws + 45154304);                       // 2 KB
  float* pbeta  = (float*)(ws + 45156352);                       // 2 KB
  float* bb     = (float*)(ws + 45158400);                       // 4 KB

  prep_kernel<<<2624, 256, 0, stream>>>(x, mask, W_up, b_up, W_f, dp,
                                        Wf_bf, WupT, bb, hv, carry, lbeta, cbeta);
  mid2_kernel<<<272, 256, 0, stream>>>(Wf_bf, WupT, Wc, carry, cbeta, dp,
                                       Pbf, pbeta);
  pout_kernel<<<128, 256, 0, stream>>>(Pbf, Wc, pbeta, bb, Pout);
  gemm_main<<<256, 512, 0, stream>>>(hv, Wc, Pout, lbeta, bb, b_f, dp, out);
}

// Round 5
// 190.964 us; speedup vs baseline: 1.0152x; 1.0152x over previous
//
#include <hip/hip_runtime.h>
#include <hip/hip_bf16.h>
#include <cstdint>
#include <cstddef>

// Sizes fixed by the reference problem.
#define DMODEL 1024
#define BATCH  4
#define SEQ    4096
#define BSROWS (BATCH*SEQ)     // 16384
#define CHUNK  32
#define NCHUNK (SEQ/CHUNK)     // 128
#define NCH_T  (BATCH*NCHUNK)  // 512 total chunks

typedef __attribute__((ext_vector_type(8))) short bf16x8;
typedef __attribute__((ext_vector_type(4))) float f32x4;

// ---- helpers ---------------------------------------------------------------

__device__ __forceinline__ unsigned short f2bf(float f) {
  union { float f; uint32_t u; } v; v.f = f;
  uint32_t u = v.u;
  u += 0x7FFFu + ((u >> 16) & 1u);   // round-to-nearest-even
  return (unsigned short)(u >> 16);
}

__device__ __forceinline__ float sigmoid_dev(const float* dp) {
  return 1.0f / (1.0f + expf(-dp[0]));
}

typedef __attribute__((address_space(1))) void void_g;
typedef __attribute__((address_space(3))) void void_l;

__device__ __forceinline__ void gl2lds16(const void* g, void* l) {
  __builtin_amdgcn_global_load_lds((void_g*)g, (void_l*)l, 16, 0, 0);
}

// ---- 64x64-tile NT K-loop (BK=64, XOR-8 swizzle) — used by mid2/pout -------
// Ring-3 LDS pipeline, counted vmcnt(4), raw s_barrier, 1 barrier per K-step.
// (Unchanged — passing since round 1.)
__device__ __forceinline__ void kloop64(
    const unsigned short* __restrict__ A, const unsigned short* __restrict__ B,
    int m0, int n0, f32x4 acc[2][2],
    unsigned short* As, unsigned short* Bs, int tid) {
  int lane = tid & 63, w = tid >> 6, wm = w & 1, wn = w >> 1;
  int quad = lane >> 4, l16 = lane & 15;
  int r = tid >> 3, cch = tid & 7;
  int g = cch ^ (r & 7);

  auto stage = [&](int t, int slot) {
    int k0 = t * 64;
    unsigned short* dA = As + slot * 4096;
    unsigned short* dB = Bs + slot * 4096;
    gl2lds16(A + (size_t)(m0 + r) * DMODEL + k0 + g * 8,      dA + r * 64 + cch * 8);
    gl2lds16(A + (size_t)(m0 + 32 + r) * DMODEL + k0 + g * 8, dA + (32 + r) * 64 + cch * 8);
    gl2lds16(B + (size_t)(n0 + r) * DMODEL + k0 + g * 8,      dB + r * 64 + cch * 8);
    gl2lds16(B + (size_t)(n0 + 32 + r) * DMODEL + k0 + g * 8, dB + (32 + r) * 64 + cch * 8);
  };
  auto compute = [&](int slot) {
    const bf16x8* Av = (const bf16x8*)(As + slot * 4096);
    const bf16x8* Bv = (const bf16x8*)(Bs + slot * 4096);
    #pragma unroll
    for (int kk = 0; kk < 2; ++kk) {
      bf16x8 af[2], bfr[2];
      #pragma unroll
      for (int i = 0; i < 2; ++i) {
        int rowA = wm * 32 + i * 16 + l16;
        af[i]  = Av[rowA * 8 + ((kk * 4 + quad) ^ (l16 & 7))];
        int rowB = wn * 32 + i * 16 + l16;
        bfr[i] = Bv[rowB * 8 + ((kk * 4 + quad) ^ (l16 & 7))];
      }
      __builtin_amdgcn_s_setprio(1);
      #pragma unroll
      for (int i = 0; i < 2; ++i)
        #pragma unroll
        for (int j = 0; j < 2; ++j)
          acc[i][j] = __builtin_amdgcn_mfma_f32_16x16x32_bf16(af[i], bfr[j], acc[i][j], 0, 0, 0);
      __builtin_amdgcn_s_setprio(0);
    }
  };

  stage(0, 0); stage(1, 1);
  asm volatile("s_waitcnt vmcnt(4)" ::: "memory");
  __builtin_amdgcn_s_barrier();
  asm volatile("" ::: "memory");
  int cur = 0;
  for (int t = 0; t < 14; ++t) {
    int ns = cur + 2; if (ns >= 3) ns -= 3;
    stage(t + 2, ns);
    compute(cur);
    asm volatile("s_waitcnt vmcnt(4)" ::: "memory");
    __builtin_amdgcn_s_barrier();
    asm volatile("" ::: "memory");
    cur = (cur == 2) ? 0 : cur + 1;
  }
  compute(cur);                                        // tile 14
  asm volatile("s_waitcnt vmcnt(0)" ::: "memory");
  __builtin_amdgcn_s_barrier();
  asm volatile("" ::: "memory");
  cur = (cur == 2) ? 0 : cur + 1;
  compute(cur);                                        // tile 15
}

// ---- fused prep ------------------------------------------------------------
// blocks [0,512)    : single-pass local scan: hv = local scan (bf16) + carry
// blocks [512,1536) : W_f row e = blk-512 -> bf16, fused bb[e]=dot(W_f[e],b_up)
// blocks [1536,2560): W_up f32 [c][d] -> bf16 transposed [d][c] (ushort4 store)
// blocks [2560,2624): lbeta/cbeta via 5-step Kogge-Stone shuffle scan
__global__ __launch_bounds__(256) void prep_kernel(
    const float* __restrict__ x, const float* __restrict__ mask,
    const float* __restrict__ W_up, const float* __restrict__ b_up,
    const float* __restrict__ W_f, const float* __restrict__ dp,
    unsigned short* __restrict__ Wf_bf, unsigned short* __restrict__ WupT,
    float* __restrict__ bb, unsigned short* __restrict__ hv,
    float* __restrict__ carry, float* __restrict__ lbeta,
    float* __restrict__ cbeta) {
  __shared__ float tile[32][33];
  int blk = blockIdx.x;
  int tid = threadIdx.x;

  if (blk < 512) {
    float decay = sigmoid_dev(dp);
    int b = blk / NCHUNK, c = blk % NCHUNK;
    int base = b * SEQ + c * CHUNK;
    const float4* xp = (const float4*)(x + (size_t)base * DMODEL);
    const float4* mp4 = (const float4*)(mask + base);
    float mreg[32];
    #pragma unroll
    for (int q = 0; q < 8; ++q) {
      float4 t = mp4[q];
      mreg[q * 4 + 0] = t.x; mreg[q * 4 + 1] = t.y;
      mreg[q * 4 + 2] = t.z; mreg[q * 4 + 3] = t.w;
    }
    float4 h = make_float4(0.f, 0.f, 0.f, 0.f);
    #pragma unroll
    for (int s = 0; s < CHUNK; ++s) {
      float m = mreg[s];
      float4 xv = xp[(size_t)s * (DMODEL / 4) + tid];
      h.x = decay * h.x + m * xv.x;
      h.y = decay * h.y + m * xv.y;
      h.z = decay * h.z + m * xv.z;
      h.w = decay * h.w + m * xv.w;
      ushort4 o;
      o.x = f2bf(h.x); o.y = f2bf(h.y); o.z = f2bf(h.z); o.w = f2bf(h.w);
      ((ushort4*)hv)[(size_t)(base + s) * (DMODEL / 4) + tid] = o;
    }
    ((float4*)carry)[(size_t)blk * (DMODEL / 4) + tid] = h;
  } else if (blk < 1536) {
    int e = blk - 512;
    int lane = tid & 63, w = tid >> 6;
    float4 v = ((const float4*)(W_f + (size_t)e * DMODEL))[tid];
    float4 bu = ((const float4*)b_up)[tid];
    ushort4 o;
    o.x = f2bf(v.x); o.y = f2bf(v.y); o.z = f2bf(v.z); o.w = f2bf(v.w);
    ((ushort4*)(Wf_bf + (size_t)e * DMODEL))[tid] = o;
    float s = v.x * bu.x + v.y * bu.y + v.z * bu.z + v.w * bu.w;
    #pragma unroll
    for (int off = 32; off; off >>= 1) s += __shfl_down(s, off);
    if (lane == 0) ((float*)tile)[w] = s;
    __syncthreads();
    if (tid == 0)
      bb[e] = ((float*)tile)[0] + ((float*)tile)[1] +
              ((float*)tile)[2] + ((float*)tile)[3];
  } else if (blk < 2560) {
    // transpose 32x32 tile; vectorized ushort4 store
    int id = blk - 1536;
    int bx = id & 31, by = id >> 5;
    int tx = tid & 31, ty = tid >> 5;   // 32 x 8
    int xx = bx * 32 + tx;
    int y0 = by * 32;
    for (int j = ty; j < 32; j += 8)
      tile[j][tx] = W_up[(size_t)(y0 + j) * DMODEL + xx];
    __syncthreads();
    int dd = tid >> 3;            // 0..31
    int c4 = (tid & 7) * 4;       // 0,4,...,28
    ushort4 o;
    o.x = f2bf(tile[c4 + 0][dd]);
    o.y = f2bf(tile[c4 + 1][dd]);
    o.z = f2bf(tile[c4 + 2][dd]);
    o.w = f2bf(tile[c4 + 3][dd]);
    *(ushort4*)(WupT + (size_t)(bx * 32 + dd) * DMODEL + y0 + c4) = o;
  } else {
    // beta local scans via 5-step Kogge-Stone (segments wave-aligned)
    float decay = sigmoid_dev(dp);
    int t = (blk - 2560) * 256 + tid;     // 0..16383 global row
    int s = t & 31;
    float h = mask[t];
    float wgt = decay;
    #pragma unroll
    for (int off = 1; off < 32; off <<= 1) {
      float up = __shfl_up(h, off);
      if (s >= off) h += wgt * up;
      wgt = wgt * wgt;
    }
    lbeta[t] = h;
    if (s == 31) cbeta[t >> 5] = h;
  }
}

// ---- mid2: gemm_wc (256 blocks, 64x64) + chunk-level scan (16 blocks) ------
__global__ __launch_bounds__(256) void mid2_kernel(
    const unsigned short* __restrict__ Wf_bf,
    const unsigned short* __restrict__ WupT,
    unsigned short* __restrict__ Wc,
    const float* __restrict__ carry, const float* __restrict__ cbeta,
    const float* __restrict__ dp,
    unsigned short* __restrict__ Pbf, float* __restrict__ pbeta) {
  __shared__ unsigned short As[3 * 64 * 64];   // 24 KB (ring-3)
  __shared__ unsigned short Bs[3 * 64 * 64];   // 24 KB
  int tid = threadIdx.x;
  if (blockIdx.x < 256) {
    int mt = blockIdx.x >> 4, nt = blockIdx.x & 15;
    f32x4 acc[2][2] = {};
    kloop64(Wf_bf, WupT, mt * 64, nt * 64, acc, As, Bs, tid);
    int lane = tid & 63, w = tid >> 6, wm = w & 1, wn = w >> 1;
    int quad = lane >> 4, l16 = lane & 15;
    #pragma unroll
    for (int j = 0; j < 2; ++j) {
      int col = nt * 64 + wn * 32 + j * 16 + l16;
      #pragma unroll
      for (int i = 0; i < 2; ++i) {
        int rowb = mt * 64 + wm * 32 + i * 16 + quad * 4;
        #pragma unroll
        for (int rr = 0; rr < 4; ++rr)
          Wc[(size_t)(rowb + rr) * DMODEL + col] = f2bf(acc[i][j][rr]);
      }
    }
  } else {
    float decay = sigmoid_dev(dp);
    float dL = powf(decay, (float)CHUNK);
    int gid = (blockIdx.x - 256) * 256 + tid;   // 0 .. 4095
    int b = gid >> 10, dd = gid & 1023;
    float P = 0.f;
    for (int c0 = 0; c0 < NCHUNK; c0 += 8) {
      float v[8];
      #pragma unroll
      for (int j = 0; j < 8; ++j)
        v[j] = carry[(size_t)(b * NCHUNK + c0 + j) * DMODEL + dd];
      #pragma unroll
      for (int j = 0; j < 8; ++j) {
        Pbf[(size_t)(b * NCHUNK + c0 + j) * DMODEL + dd] = f2bf(P);
        P = dL * P + v[j];
      }
    }
    if (dd == 0) {
      float Pb = 0.f;
      for (int c0 = 0; c0 < NCHUNK; c0 += 16) {
        float v[16];
        #pragma unroll
        for (int j = 0; j < 16; ++j) v[j] = cbeta[b * NCHUNK + c0 + j];
        #pragma unroll
        for (int j = 0; j < 16; ++j) {
          pbeta[b * NCHUNK + c0 + j] = Pb;
          Pb = dL * Pb + v[j];
        }
      }
    }
  }
}

// ---- pout: Pout[c][e] = sum_d Pbf[c][d]*Wc[e][d] + pbeta[c]*bb[e] ----------
__global__ __launch_bounds__(256) void pout_kernel(
    const unsigned short* __restrict__ Pbf,
    const unsigned short* __restrict__ Wc,
    const float* __restrict__ pbeta, const float* __restrict__ bb,
    float* __restrict__ Pout) {
  __shared__ unsigned short As[3 * 64 * 64];   // 24 KB (ring-3)
  __shared__ unsigned short Bs[3 * 64 * 64];   // 24 KB
  int tid = threadIdx.x;
  int mt = blockIdx.x >> 4, nt = blockIdx.x & 15;  // 8 x 16
  f32x4 acc[2][2] = {};
  kloop64(Pbf, Wc, mt * 64, nt * 64, acc, As, Bs, tid);
  int lane = tid & 63, w = tid >> 6, wm = w & 1, wn = w >> 1;
  int quad = lane >> 4, l16 = lane & 15;
  #pragma unroll
  for (int j = 0; j < 2; ++j) {
    int col = nt * 64 + wn * 32 + j * 16 + l16;
    float bbv = bb[col];
    #pragma unroll
    for (int i = 0; i < 2; ++i) {
      int rowb = mt * 64 + wm * 32 + i * 16 + quad * 4;
      #pragma unroll
      for (int rr = 0; rr < 4; ++rr) {
        int row = rowb + rr;
        Pout[(size_t)row * DMODEL + col] = acc[i][j][rr] + pbeta[row] * bbv;
      }
    }
  }
}

// ---- main GEMM: out = hv@Wc^T + decay^(s+1)*Pout[chunk] + lbeta*bb + b_f ---
// r5 structure: 256x256 tile, 512 threads (8 waves 2Mx4N), BK=64, classic
// 2-buffer ping-pong (128 KB LDS, 1 block/CU, 256 blocks = 1/CU, no tail).
// Per K-tile: stage next tile FIRST (8 gl2lds), then 24 ds_read_b128 + 64
// MFMA per wave (~620 cyc/SIMD), then vmcnt(0)+barrier. Compute-per-barrier
// (620cy) > load latency (~300-400cy L2/L3), so the drain is fully hidden —
// r1/r4 showed counted-vmcnt/fine-phase machinery is not the lever here;
// compute-per-barrier is (r3: BK=32, 310cy/barrier -> 25% MfmaUtil).
// 16 barriers total vs r3's 32. Swizzle algebra identical to kloop64
// (verified, 0 bank conflicts): source pre-swizzle g=cch^(r&7), read slot
// (kk*4+quad)^(row&7).
__global__ __launch_bounds__(512) void gemm_main(
    const unsigned short* __restrict__ A,    // hv (local scans) bf16 [16384][1024]
    const unsigned short* __restrict__ Bm,   // Wc bf16 [1024][1024] rows=e
    const float* __restrict__ Pout,          // [512][1024]
    const float* __restrict__ lbeta,
    const float* __restrict__ bb,
    const float* __restrict__ bias_f,
    const float* __restrict__ dp,
    float* __restrict__ out) {
  __shared__ unsigned short As[2 * 256 * 64];   // 64 KB (dbuf)
  __shared__ unsigned short Bs[2 * 256 * 64];   // 64 KB
  __shared__ float dpow[CHUNK];
  const int TSLOT = 256 * 64;
  int tid = threadIdx.x;
  if (tid < CHUNK) {
    float decay = sigmoid_dev(dp);
    dpow[tid] = powf(decay, (float)(tid + 1));
  }

  int lane = tid & 63, wid = tid >> 6;
  int wm = wid >> 2, wn = wid & 3;            // 2M x 4N waves
  int quad = lane >> 4, l16 = lane & 15;
  int r = tid >> 3, cch = tid & 7;            // staging: 64 rows x 8 chunks
  int g = cch ^ (r & 7);                      // pre-swizzled global chunk

  // XCD-aware mapping: each XCD owns 8 contiguous m-tiles x all 4 n-tiles
  // (A-panel 4 MB = exactly one XCD L2; fetched once, reused by 4 n-blocks).
  int bid = blockIdx.x;
  int xcd = bid & 7, jb = bid >> 3;
  int m0 = (xcd * 8 + (jb >> 2)) * 256;       // 64 m-tiles
  int n0 = (jb & 3) * 256;                    // 4 n-tiles

  f32x4 acc[8][4] = {};

  auto stageT = [&](int t, int p) {
    int k0 = t * 64;
    unsigned short* dA = As + p * TSLOT;
    unsigned short* dB = Bs + p * TSLOT;
    #pragma unroll
    for (int q = 0; q < 4; ++q)
      gl2lds16(A + (size_t)(m0 + q * 64 + r) * DMODEL + k0 + g * 8,
               dA + (q * 64 + r) * 64 + cch * 8);
    #pragma unroll
    for (int q = 0; q < 4; ++q)
      gl2lds16(Bm + (size_t)(n0 + q * 64 + r) * DMODEL + k0 + g * 8,
               dB + (q * 64 + r) * 64 + cch * 8);
  };
  auto compute = [&](int p) {
    const bf16x8* Av = (const bf16x8*)(As + p * TSLOT);
    const bf16x8* Bv = (const bf16x8*)(Bs + p * TSLOT);
    #pragma unroll
    for (int kk = 0; kk < 2; ++kk) {
      bf16x8 bfr[4];
      #pragma unroll
      for (int j = 0; j < 4; ++j) {
        int rowB = wn * 64 + j * 16 + l16;
        bfr[j] = Bv[rowB * 8 + ((kk * 4 + quad) ^ (l16 & 7))];
      }
      #pragma unroll
      for (int i = 0; i < 8; ++i) {
        int rowA = wm * 128 + i * 16 + l16;
        bf16x8 af = Av[rowA * 8 + ((kk * 4 + quad) ^ (l16 & 7))];
        __builtin_amdgcn_s_setprio(1);
        #pragma unroll
        for (int j = 0; j < 4; ++j)
          acc[i][j] = __builtin_amdgcn_mfma_f32_16x16x32_bf16(af, bfr[j], acc[i][j], 0, 0, 0);
        __builtin_amdgcn_s_setprio(0);
      }
    }
  };

  // Prologue: tile 0 -> buf 0; __syncthreads drains vmcnt+lgkm (tile 0
  // landed for all waves) and makes dpow visible.
  stageT(0, 0);
  __syncthreads();

  // Main loop: 16 K-tiles. Stage t+1 into buf p^1 (freed by the barrier at
  // the end of t-1), compute t from buf p, then vmcnt(0)+barrier: t+1's
  // loads (issued ~620 cyc of MFMA ago) are landed, and buf p is released.
  for (int t = 0; t < 15; ++t) {
    int p = t & 1;
    stageT(t + 1, p ^ 1);
    compute(p);
    asm volatile("s_waitcnt vmcnt(0)" ::: "memory");
    __builtin_amdgcn_s_barrier();
    asm volatile("" ::: "memory");
  }
  compute(1);                                 // tile 15 (buf 1)

  // Epilogue — j innermost: 16-lane groups write 4 consecutive 64 B segments
  // per row; lbeta/dpow hoisted per row.
  float bbv[4], bfv[4];
  #pragma unroll
  for (int j = 0; j < 4; ++j) {
    int col = n0 + wn * 64 + j * 16 + l16;
    bbv[j] = bb[col];
    bfv[j] = bias_f[col];
  }
  #pragma unroll
  for (int i = 0; i < 8; ++i) {
    #pragma unroll
    for (int rr = 0; rr < 4; ++rr) {
      int row = m0 + wm * 128 + i * 16 + quad * 4 + rr;
      float lb  = lbeta[row];
      float dpw = dpow[row & 31];
      const float* poRow = Pout + (size_t)(row >> 5) * DMODEL;
      float* outRow = out + (size_t)row * DMODEL;
      #pragma unroll
      for (int j = 0; j < 4; ++j) {
        int col = n0 + wn * 64 + j * 16 + l16;
        outRow[col] = acc[i][j][rr] + dpw * poRow[col] + lb * bbv[j] + bfv[j];
      }
    }
  }
}

// ---- launch ----------------------------------------------------------------

extern "C" void kernel_launch(void* const* d_in, const int* in_sizes, int n_in,
                              void* d_out, int out_size, void* d_ws, size_t ws_size,
                              hipStream_t stream) {
  const float* x    = (const float*)d_in[0];
  const float* mask = (const float*)d_in[1];
  const float* W_up = (const float*)d_in[2];
  const float* b_up = (const float*)d_in[3];
  const float* W_f  = (const float*)d_in[4];
  const float* b_f  = (const float*)d_in[5];
  const float* dp   = (const float*)d_in[6];
  float* out = (float*)d_out;

  char* ws = (char*)d_ws;
  unsigned short* hv    = (unsigned short*)(ws);                 // 32 MB
  unsigned short* Wc    = (unsigned short*)(ws + 33554432);      // 2 MB
  unsigned short* Wf_bf = (unsigned short*)(ws + 35651584);      // 2 MB
  unsigned short* WupT  = (unsigned short*)(ws + 37748736);      // 2 MB
  float* carry  = (float*)(ws + 39845888);                       // 2 MB
  unsigned short* Pbf = (unsigned short*)(ws + 41943040);        // 1 MB
  float* Pout   = (float*)(ws + 42991616);                       // 2 MB
  float* lbeta  = (float*)(ws + 45088768);                       // 64 KB
  float* cbeta  = (float*)(ws + 45154304);                       // 2 KB
  float* pbeta  = (float*)(ws + 45156352);                       // 2 KB
  float* bb     = (float*)(ws + 45158400);                       // 4 KB

  prep_kernel<<<2624, 256, 0, stream>>>(x, mask, W_up, b_up, W_f, dp,
                                        Wf_bf, WupT, bb, hv, carry, lbeta, cbeta);
  mid2_kernel<<<272, 256, 0, stream>>>(Wf_bf, WupT, Wc, carry, cbeta, dp,
                                       Pbf, pbeta);
  pout_kernel<<<128, 256, 0, stream>>>(Pbf, Wc, pbeta, bb, Pout);
  gemm_main<<<256, 512, 0, stream>>>(hv, Wc, Pout, lbeta, bb, b_f, dp, out);
}

// Round 6
// 185.284 us; speedup vs baseline: 1.0463x; 1.0307x over previous
//
#include <hip/hip_runtime.h>
#include <hip/hip_bf16.h>
#include <cstdint>
#include <cstddef>

// Sizes fixed by the reference problem.
#define DMODEL 1024
#define BATCH  4
#define SEQ    4096
#define BSROWS (BATCH*SEQ)     // 16384
#define CHUNK  32
#define NCHUNK (SEQ/CHUNK)     // 128
#define NCH_T  (BATCH*NCHUNK)  // 512 total chunks

typedef __attribute__((ext_vector_type(8))) short bf16x8;
typedef __attribute__((ext_vector_type(4))) float f32x4;

// ---- helpers ---------------------------------------------------------------

__device__ __forceinline__ unsigned short f2bf(float f) {
  union { float f; uint32_t u; } v; v.f = f;
  uint32_t u = v.u;
  u += 0x7FFFu + ((u >> 16) & 1u);   // round-to-nearest-even
  return (unsigned short)(u >> 16);
}

__device__ __forceinline__ float sigmoid_dev(const float* dp) {
  return 1.0f / (1.0f + expf(-dp[0]));
}

typedef __attribute__((address_space(1))) void void_g;
typedef __attribute__((address_space(3))) void void_l;

__device__ __forceinline__ void gl2lds16(const void* g, void* l) {
  __builtin_amdgcn_global_load_lds((void_g*)g, (void_l*)l, 16, 0, 0);
}

// ---- 64x64-tile NT K-loop (BK=64, XOR-8 swizzle) — used by mid2 ------------
// Ring-3 LDS pipeline, counted vmcnt(4), raw s_barrier, 1 barrier per K-step.
// (Unchanged — passing since round 1.)
__device__ __forceinline__ void kloop64(
    const unsigned short* __restrict__ A, const unsigned short* __restrict__ B,
    int m0, int n0, f32x4 acc[2][2],
    unsigned short* As, unsigned short* Bs, int tid) {
  int lane = tid & 63, w = tid >> 6, wm = w & 1, wn = w >> 1;
  int quad = lane >> 4, l16 = lane & 15;
  int r = tid >> 3, cch = tid & 7;
  int g = cch ^ (r & 7);

  auto stage = [&](int t, int slot) {
    int k0 = t * 64;
    unsigned short* dA = As + slot * 4096;
    unsigned short* dB = Bs + slot * 4096;
    gl2lds16(A + (size_t)(m0 + r) * DMODEL + k0 + g * 8,      dA + r * 64 + cch * 8);
    gl2lds16(A + (size_t)(m0 + 32 + r) * DMODEL + k0 + g * 8, dA + (32 + r) * 64 + cch * 8);
    gl2lds16(B + (size_t)(n0 + r) * DMODEL + k0 + g * 8,      dB + r * 64 + cch * 8);
    gl2lds16(B + (size_t)(n0 + 32 + r) * DMODEL + k0 + g * 8, dB + (32 + r) * 64 + cch * 8);
  };
  auto compute = [&](int slot) {
    const bf16x8* Av = (const bf16x8*)(As + slot * 4096);
    const bf16x8* Bv = (const bf16x8*)(Bs + slot * 4096);
    #pragma unroll
    for (int kk = 0; kk < 2; ++kk) {
      bf16x8 af[2], bfr[2];
      #pragma unroll
      for (int i = 0; i < 2; ++i) {
        int rowA = wm * 32 + i * 16 + l16;
        af[i]  = Av[rowA * 8 + ((kk * 4 + quad) ^ (l16 & 7))];
        int rowB = wn * 32 + i * 16 + l16;
        bfr[i] = Bv[rowB * 8 + ((kk * 4 + quad) ^ (l16 & 7))];
      }
      __builtin_amdgcn_s_setprio(1);
      #pragma unroll
      for (int i = 0; i < 2; ++i)
        #pragma unroll
        for (int j = 0; j < 2; ++j)
          acc[i][j] = __builtin_amdgcn_mfma_f32_16x16x32_bf16(af[i], bfr[j], acc[i][j], 0, 0, 0);
      __builtin_amdgcn_s_setprio(0);
    }
  };

  stage(0, 0); stage(1, 1);
  asm volatile("s_waitcnt vmcnt(4)" ::: "memory");
  __builtin_amdgcn_s_barrier();
  asm volatile("" ::: "memory");
  int cur = 0;
  for (int t = 0; t < 14; ++t) {
    int ns = cur + 2; if (ns >= 3) ns -= 3;
    stage(t + 2, ns);
    compute(cur);
    asm volatile("s_waitcnt vmcnt(4)" ::: "memory");
    __builtin_amdgcn_s_barrier();
    asm volatile("" ::: "memory");
    cur = (cur == 2) ? 0 : cur + 1;
  }
  compute(cur);                                        // tile 14
  asm volatile("s_waitcnt vmcnt(0)" ::: "memory");
  __builtin_amdgcn_s_barrier();
  asm volatile("" ::: "memory");
  cur = (cur == 2) ? 0 : cur + 1;
  compute(cur);                                        // tile 15
}

// ---- fused prep ------------------------------------------------------------
// blocks [0,512)    : single-pass local scan: hv = local scan (bf16) + carry
// blocks [512,1536) : W_f row e = blk-512 -> bf16, fused bb[e]=dot(W_f[e],b_up)
// blocks [1536,2560): W_up f32 [c][d] -> bf16 transposed [d][c] (ushort4 store)
// blocks [2560,2624): lbeta/cbeta via 5-step Kogge-Stone shuffle scan
__global__ __launch_bounds__(256) void prep_kernel(
    const float* __restrict__ x, const float* __restrict__ mask,
    const float* __restrict__ W_up, const float* __restrict__ b_up,
    const float* __restrict__ W_f, const float* __restrict__ dp,
    unsigned short* __restrict__ Wf_bf, unsigned short* __restrict__ WupT,
    float* __restrict__ bb, unsigned short* __restrict__ hv,
    float* __restrict__ carry, float* __restrict__ lbeta,
    float* __restrict__ cbeta) {
  __shared__ float tile[32][33];
  int blk = blockIdx.x;
  int tid = threadIdx.x;

  if (blk < 512) {
    float decay = sigmoid_dev(dp);
    int b = blk / NCHUNK, c = blk % NCHUNK;
    int base = b * SEQ + c * CHUNK;
    const float4* xp = (const float4*)(x + (size_t)base * DMODEL);
    const float4* mp4 = (const float4*)(mask + base);
    float mreg[32];
    #pragma unroll
    for (int q = 0; q < 8; ++q) {
      float4 t = mp4[q];
      mreg[q * 4 + 0] = t.x; mreg[q * 4 + 1] = t.y;
      mreg[q * 4 + 2] = t.z; mreg[q * 4 + 3] = t.w;
    }
    float4 h = make_float4(0.f, 0.f, 0.f, 0.f);
    #pragma unroll
    for (int s = 0; s < CHUNK; ++s) {
      float m = mreg[s];
      float4 xv = xp[(size_t)s * (DMODEL / 4) + tid];
      h.x = decay * h.x + m * xv.x;
      h.y = decay * h.y + m * xv.y;
      h.z = decay * h.z + m * xv.z;
      h.w = decay * h.w + m * xv.w;
      ushort4 o;
      o.x = f2bf(h.x); o.y = f2bf(h.y); o.z = f2bf(h.z); o.w = f2bf(h.w);
      ((ushort4*)hv)[(size_t)(base + s) * (DMODEL / 4) + tid] = o;
    }
    ((float4*)carry)[(size_t)blk * (DMODEL / 4) + tid] = h;
  } else if (blk < 1536) {
    int e = blk - 512;
    int lane = tid & 63, w = tid >> 6;
    float4 v = ((const float4*)(W_f + (size_t)e * DMODEL))[tid];
    float4 bu = ((const float4*)b_up)[tid];
    ushort4 o;
    o.x = f2bf(v.x); o.y = f2bf(v.y); o.z = f2bf(v.z); o.w = f2bf(v.w);
    ((ushort4*)(Wf_bf + (size_t)e * DMODEL))[tid] = o;
    float s = v.x * bu.x + v.y * bu.y + v.z * bu.z + v.w * bu.w;
    #pragma unroll
    for (int off = 32; off; off >>= 1) s += __shfl_down(s, off);
    if (lane == 0) ((float*)tile)[w] = s;
    __syncthreads();
    if (tid == 0)
      bb[e] = ((float*)tile)[0] + ((float*)tile)[1] +
              ((float*)tile)[2] + ((float*)tile)[3];
  } else if (blk < 2560) {
    // transpose 32x32 tile; vectorized ushort4 store
    int id = blk - 1536;
    int bx = id & 31, by = id >> 5;
    int tx = tid & 31, ty = tid >> 5;   // 32 x 8
    int xx = bx * 32 + tx;
    int y0 = by * 32;
    for (int j = ty; j < 32; j += 8)
      tile[j][tx] = W_up[(size_t)(y0 + j) * DMODEL + xx];
    __syncthreads();
    int dd = tid >> 3;            // 0..31
    int c4 = (tid & 7) * 4;       // 0,4,...,28
    ushort4 o;
    o.x = f2bf(tile[c4 + 0][dd]);
    o.y = f2bf(tile[c4 + 1][dd]);
    o.z = f2bf(tile[c4 + 2][dd]);
    o.w = f2bf(tile[c4 + 3][dd]);
    *(ushort4*)(WupT + (size_t)(bx * 32 + dd) * DMODEL + y0 + c4) = o;
  } else {
    // beta local scans via 5-step Kogge-Stone (segments wave-aligned)
    float decay = sigmoid_dev(dp);
    int t = (blk - 2560) * 256 + tid;     // 0..16383 global row
    int s = t & 31;
    float h = mask[t];
    float wgt = decay;
    #pragma unroll
    for (int off = 1; off < 32; off <<= 1) {
      float up = __shfl_up(h, off);
      if (s >= off) h += wgt * up;
      wgt = wgt * wgt;
    }
    lbeta[t] = h;
    if (s == 31) cbeta[t >> 5] = h;
  }
}

// ---- mid2: gemm_wc (256 blocks, 64x64) + chunk-level scan (16 blocks) ------
__global__ __launch_bounds__(256) void mid2_kernel(
    const unsigned short* __restrict__ Wf_bf,
    const unsigned short* __restrict__ WupT,
    unsigned short* __restrict__ Wc,
    const float* __restrict__ carry, const float* __restrict__ cbeta,
    const float* __restrict__ dp,
    unsigned short* __restrict__ Pbf, float* __restrict__ pbeta) {
  __shared__ unsigned short As[3 * 64 * 64];   // 24 KB (ring-3)
  __shared__ unsigned short Bs[3 * 64 * 64];   // 24 KB
  int tid = threadIdx.x;
  if (blockIdx.x < 256) {
    int mt = blockIdx.x >> 4, nt = blockIdx.x & 15;
    f32x4 acc[2][2] = {};
    kloop64(Wf_bf, WupT, mt * 64, nt * 64, acc, As, Bs, tid);
    int lane = tid & 63, w = tid >> 6, wm = w & 1, wn = w >> 1;
    int quad = lane >> 4, l16 = lane & 15;
    #pragma unroll
    for (int j = 0; j < 2; ++j) {
      int col = nt * 64 + wn * 32 + j * 16 + l16;
      #pragma unroll
      for (int i = 0; i < 2; ++i) {
        int rowb = mt * 64 + wm * 32 + i * 16 + quad * 4;
        #pragma unroll
        for (int rr = 0; rr < 4; ++rr)
          Wc[(size_t)(rowb + rr) * DMODEL + col] = f2bf(acc[i][j][rr]);
      }
    }
  } else {
    float decay = sigmoid_dev(dp);
    float dL = powf(decay, (float)CHUNK);
    int gid = (blockIdx.x - 256) * 256 + tid;   // 0 .. 4095
    int b = gid >> 10, dd = gid & 1023;
    float P = 0.f;
    for (int c0 = 0; c0 < NCHUNK; c0 += 8) {
      float v[8];
      #pragma unroll
      for (int j = 0; j < 8; ++j)
        v[j] = carry[(size_t)(b * NCHUNK + c0 + j) * DMODEL + dd];
      #pragma unroll
      for (int j = 0; j < 8; ++j) {
        Pbf[(size_t)(b * NCHUNK + c0 + j) * DMODEL + dd] = f2bf(P);
        P = dL * P + v[j];
      }
    }
    if (dd == 0) {
      float Pb = 0.f;
      for (int c0 = 0; c0 < NCHUNK; c0 += 16) {
        float v[16];
        #pragma unroll
        for (int j = 0; j < 16; ++j) v[j] = cbeta[b * NCHUNK + c0 + j];
        #pragma unroll
        for (int j = 0; j < 16; ++j) {
          pbeta[b * NCHUNK + c0 + j] = Pb;
          Pb = dL * Pb + v[j];
        }
      }
    }
  }
}

// ---- main GEMM (fused with pout): ------------------------------------------
// out = hv@Wc^T + decay^(s+1)*(Pbf@Wc^T + pbeta*bb) + lbeta*bb + b_f
// r6: r5's 256x256/BK=64 dbuf structure, PLUS the former pout_kernel fused in
// as a 9th M-fragment: wave 0 stages the block's 8 Pbf rows (chunks m0>>5..+7)
// per K-tile (1 extra gl2lds, source pre-swizzled), every wave adds 8 MFMAs
// (pf x bfr[j] -> Pacc[j]; rows 8-15 of the P fragment are garbage and
// discarded). Epilogue: wm==0/quad<2 waves write the valid 8x256 Pout block
// to LDS (reusing As), one __syncthreads, then each thread reads its po and
// folds pbeta*bb into the existing FMA chain. Deletes pout_kernel (its
// 128-block latency-bound dispatch + launch gap + Pout global round-trip).
// vmcnt(0) drain is per-tile and uniform-safe (wave 0 has 9 loads, others 8).
__global__ __launch_bounds__(512) void gemm_main(
    const unsigned short* __restrict__ A,    // hv (local scans) bf16 [16384][1024]
    const unsigned short* __restrict__ Bm,   // Wc bf16 [1024][1024] rows=e
    const unsigned short* __restrict__ Pbf,  // [512][1024] bf16 chunk-states
    const float* __restrict__ pbeta,
    const float* __restrict__ lbeta,
    const float* __restrict__ bb,
    const float* __restrict__ bias_f,
    const float* __restrict__ dp,
    float* __restrict__ out) {
  __shared__ unsigned short As[2 * 256 * 64];   // 64 KB (dbuf)
  __shared__ unsigned short Bs[2 * 256 * 64];   // 64 KB
  __shared__ unsigned short Ps[2 * 16 * 64];    // 4 KB (dbuf, 8 valid rows)
  __shared__ float dpow[CHUNK];
  const int TSLOT = 256 * 64;
  const int PSLOT = 16 * 64;
  int tid = threadIdx.x;
  if (tid < CHUNK) {
    float decay = sigmoid_dev(dp);
    dpow[tid] = powf(decay, (float)(tid + 1));
  }

  int lane = tid & 63, wid = tid >> 6;
  int wm = wid >> 2, wn = wid & 3;            // 2M x 4N waves
  int quad = lane >> 4, l16 = lane & 15;
  int r = tid >> 3, cch = tid & 7;            // staging: 64 rows x 8 chunks
  int g = cch ^ (r & 7);                      // pre-swizzled global chunk

  // XCD-aware mapping: each XCD owns 8 contiguous m-tiles x all 4 n-tiles.
  int bid = blockIdx.x;
  int xcd = bid & 7, jb = bid >> 3;
  int m0 = (xcd * 8 + (jb >> 2)) * 256;       // 64 m-tiles
  int n0 = (jb & 3) * 256;                    // 4 n-tiles
  int chunk0 = m0 >> 5;                       // first of this block's 8 chunks

  f32x4 acc[8][4] = {};
  f32x4 Pacc[4] = {};

  auto stageT = [&](int t, int p) {
    int k0 = t * 64;
    unsigned short* dA = As + p * TSLOT;
    unsigned short* dB = Bs + p * TSLOT;
    #pragma unroll
    for (int q = 0; q < 4; ++q)
      gl2lds16(A + (size_t)(m0 + q * 64 + r) * DMODEL + k0 + g * 8,
               dA + (q * 64 + r) * 64 + cch * 8);
    #pragma unroll
    for (int q = 0; q < 4; ++q)
      gl2lds16(Bm + (size_t)(n0 + q * 64 + r) * DMODEL + k0 + g * 8,
               dB + (q * 64 + r) * 64 + cch * 8);
    // wave 0: stage this block's 8 Pbf rows (1 KB), same XOR-8 pre-swizzle.
    if (wid == 0) {
      int rp = lane >> 3, cp = lane & 7;
      int gp = cp ^ (rp & 7);
      gl2lds16(Pbf + (size_t)(chunk0 + rp) * DMODEL + k0 + gp * 8,
               Ps + p * PSLOT + lane * 8);
    }
  };
  auto compute = [&](int p) {
    const bf16x8* Av = (const bf16x8*)(As + p * TSLOT);
    const bf16x8* Bv = (const bf16x8*)(Bs + p * TSLOT);
    const bf16x8* Pv = (const bf16x8*)(Ps + p * PSLOT);
    #pragma unroll
    for (int kk = 0; kk < 2; ++kk) {
      bf16x8 bfr[4];
      #pragma unroll
      for (int j = 0; j < 4; ++j) {
        int rowB = wn * 64 + j * 16 + l16;
        bfr[j] = Bv[rowB * 8 + ((kk * 4 + quad) ^ (l16 & 7))];
      }
      // P fragment: rows = l16 (0..7 valid, 8..15 discarded garbage)
      bf16x8 pf = Pv[l16 * 8 + ((kk * 4 + quad) ^ (l16 & 7))];
      __builtin_amdgcn_s_setprio(1);
      #pragma unroll
      for (int j = 0; j < 4; ++j)
        Pacc[j] = __builtin_amdgcn_mfma_f32_16x16x32_bf16(pf, bfr[j], Pacc[j], 0, 0, 0);
      __builtin_amdgcn_s_setprio(0);
      #pragma unroll
      for (int i = 0; i < 8; ++i) {
        int rowA = wm * 128 + i * 16 + l16;
        bf16x8 af = Av[rowA * 8 + ((kk * 4 + quad) ^ (l16 & 7))];
        __builtin_amdgcn_s_setprio(1);
        #pragma unroll
        for (int j = 0; j < 4; ++j)
          acc[i][j] = __builtin_amdgcn_mfma_f32_16x16x32_bf16(af, bfr[j], acc[i][j], 0, 0, 0);
        __builtin_amdgcn_s_setprio(0);
      }
    }
  };

  // Prologue: tile 0 -> buf 0; __syncthreads drains vmcnt+lgkm and publishes dpow.
  stageT(0, 0);
  __syncthreads();

  // Main loop: 16 K-tiles, ping-pong. Compute-per-barrier (~72 MFMA/wave)
  // exceeds load latency, so the vmcnt(0) drain is hidden under compute.
  for (int t = 0; t < 15; ++t) {
    int p = t & 1;
    stageT(t + 1, p ^ 1);
    compute(p);
    asm volatile("s_waitcnt vmcnt(0)" ::: "memory");
    __builtin_amdgcn_s_barrier();
    asm volatile("" ::: "memory");
  }
  compute(1);                                 // tile 15 (buf 1)

  // ---- fused Pout: publish the valid 8x256 block via LDS (reuse As buf0;
  // its last reader finished before the final loop barrier). Writers: wm==0
  // waves, quads 0/1 hold P rows 0..7.
  float* Plds = (float*)As;                   // [8][256] f32 = 8 KB
  if (wm == 0 && quad < 2) {
    #pragma unroll
    for (int j = 0; j < 4; ++j)
      #pragma unroll
      for (int rr = 0; rr < 4; ++rr)
        Plds[(quad * 4 + rr) * 256 + wn * 64 + j * 16 + l16] = Pacc[j][rr];
  }
  __syncthreads();

  // Epilogue — j innermost: 16-lane groups write 4 consecutive 64 B segments
  // per row; lbeta/dpow/pbeta hoisted per row.
  float bbv[4], bfv[4];
  #pragma unroll
  for (int j = 0; j < 4; ++j) {
    int col = n0 + wn * 64 + j * 16 + l16;
    bbv[j] = bb[col];
    bfv[j] = bias_f[col];
  }
  #pragma unroll
  for (int i = 0; i < 8; ++i) {
    int chl = wm * 4 + (i >> 1);              // this fragment's local chunk
    float pb = pbeta[chunk0 + chl];
    #pragma unroll
    for (int rr = 0; rr < 4; ++rr) {
      int row = m0 + wm * 128 + i * 16 + quad * 4 + rr;
      float lb  = lbeta[row];
      float dpw = dpow[row & 31];
      float* outRow = out + (size_t)row * DMODEL;
      #pragma unroll
      for (int j = 0; j < 4; ++j) {
        int col = n0 + wn * 64 + j * 16 + l16;
        float po = Plds[chl * 256 + wn * 64 + j * 16 + l16] + pb * bbv[j];
        outRow[col] = acc[i][j][rr] + dpw * po + lb * bbv[j] + bfv[j];
      }
    }
  }
}

// ---- launch ----------------------------------------------------------------

extern "C" void kernel_launch(void* const* d_in, const int* in_sizes, int n_in,
                              void* d_out, int out_size, void* d_ws, size_t ws_size,
                              hipStream_t stream) {
  const float* x    = (const float*)d_in[0];
  const float* mask = (const float*)d_in[1];
  const float* W_up = (const float*)d_in[2];
  const float* b_up = (const float*)d_in[3];
  const float* W_f  = (const float*)d_in[4];
  const float* b_f  = (const float*)d_in[5];
  const float* dp   = (const float*)d_in[6];
  float* out = (float*)d_out;

  char* ws = (char*)d_ws;
  unsigned short* hv    = (unsigned short*)(ws);                 // 32 MB
  unsigned short* Wc    = (unsigned short*)(ws + 33554432);      // 2 MB
  unsigned short* Wf_bf = (unsigned short*)(ws + 35651584);      // 2 MB
  unsigned short* WupT  = (unsigned short*)(ws + 37748736);      // 2 MB
  float* carry  = (float*)(ws + 39845888);                       // 2 MB
  unsigned short* Pbf = (unsigned short*)(ws + 41943040);        // 1 MB
  float* lbeta  = (float*)(ws + 45088768);                       // 64 KB
  float* cbeta  = (float*)(ws + 45154304);                       // 2 KB
  float* pbeta  = (float*)(ws + 45156352);                       // 2 KB
  float* bb     = (float*)(ws + 45158400);                       // 4 KB

  prep_kernel<<<2624, 256, 0, stream>>>(x, mask, W_up, b_up, W_f, dp,
                                        Wf_bf, WupT, bb, hv, carry, lbeta, cbeta);
  mid2_kernel<<<272, 256, 0, stream>>>(Wf_bf, WupT, Wc, carry, cbeta, dp,
                                       Pbf, pbeta);
  gemm_main<<<256, 512, 0, stream>>>(hv, Wc, Pbf, pbeta, lbeta, bb, b_f, dp, out);
}